// Round 12
// baseline (363.891 us; speedup 1.0000x reference)
//
#include <hip/hip_runtime.h>
#include <hip/hip_fp16.h>

#define N_NODES 50000
#define N_EDGES 800000
#define NB_SCAN 49          // ceil(50000 / 1024)
#define DEG_PAD (NB_SCAN * 1024)   // 50176, zero-padded so int4 loads are unguarded
#define NBKT 196            // ceil(50000 / 256) coarse buckets (dst >> 8)
#define EPB_BIN 4096        // edges per k_bin block
#define NB_BIN ((N_EDGES + EPB_BIN - 1) / EPB_BIN)   // 196

static __device__ __forceinline__ float lrelu(float x) { return fmaxf(x, 0.2f * x); }
static __device__ __forceinline__ float to_f(float x) { return x; }
static __device__ __forceinline__ float to_f(__half x) { return __half2float(x); }

// ---------------- CSR build ----------------
__global__ void k_count(const int* __restrict__ dst, int* __restrict__ deg) {
    int e = blockIdx.x * blockDim.x + threadIdx.x;
    if (e < N_EDGES) atomicAdd(&deg[dst[e]], 1);
}

__global__ void __launch_bounds__(256) k_scanA(const int* __restrict__ deg,
                                               int* __restrict__ bsum) {
    const int t = threadIdx.x;
    const int b = blockIdx.x;
    const int base = (b * 256 + t) * 4;
    const int4 v = *reinterpret_cast<const int4*>(deg + base);  // padded: safe
    int s = v.x + v.y + v.z + v.w;
#pragma unroll
    for (int off = 32; off > 0; off >>= 1) s += __shfl_down(s, off);
    __shared__ int ws[4];
    if ((t & 63) == 0) ws[t >> 6] = s;
    __syncthreads();
    if (t == 0) bsum[b] = ws[0] + ws[1] + ws[2] + ws[3];
}

__global__ void __launch_bounds__(64) k_scanB(const int* __restrict__ bsum,
                                              int* __restrict__ boff,
                                              int* __restrict__ rowp) {
    const int t = threadIdx.x;
    const int v = (t < NB_SCAN) ? bsum[t] : 0;
    int inc = v;
#pragma unroll
    for (int off = 1; off < 64; off <<= 1) {
        const int u = __shfl_up(inc, off);
        if (t >= off) inc += u;
    }
    if (t < NB_SCAN) boff[t] = inc - v;
    if (t == 0) rowp[N_NODES] = N_EDGES;
}

__global__ void __launch_bounds__(256) k_scanC(const int* __restrict__ deg,
                                               const int* __restrict__ boff,
                                               int* __restrict__ rowp) {
    const int t = threadIdx.x;
    const int b = blockIdx.x;
    const int lane = t & 63;
    const int wv = t >> 6;
    const int base = (b * 256 + t) * 4;
    const int4 v = *reinterpret_cast<const int4*>(deg + base);
    const int s = v.x + v.y + v.z + v.w;
    int inc = s;
#pragma unroll
    for (int off = 1; off < 64; off <<= 1) {
        const int u = __shfl_up(inc, off);
        if (lane >= off) inc += u;
    }
    __shared__ int wsum[4];
    if (lane == 63) wsum[wv] = inc;
    __syncthreads();
    int add = boff[b];
    for (int w = 0; w < wv; ++w) add += wsum[w];
    const int exc = add + inc - s;
    if (base < N_NODES) rowp[base] = exc;
    if (base + 1 < N_NODES) rowp[base + 1] = exc + v.x;
    if (base + 2 < N_NODES) rowp[base + 2] = exc + v.x + v.y;
    if (base + 3 < N_NODES) rowp[base + 3] = exc + v.x + v.y + v.z;
}

// ---------------- binned scatter (two phase, XCD-local line ownership) -------
__global__ void __launch_bounds__(256) k_bin(const int* __restrict__ src,
                                             const int* __restrict__ dst,
                                             const int* __restrict__ rowp,
                                             int* __restrict__ bfill,
                                             int2* __restrict__ stage) {
    __shared__ int lcnt[NBKT];
    __shared__ int gb[NBKT];
    __shared__ int lf[NBKT];
    const int t = threadIdx.x;
    const int e0 = blockIdx.x * EPB_BIN;
    for (int i = t; i < NBKT; i += 256) lcnt[i] = 0;
    __syncthreads();
    int dcache[16];
#pragma unroll
    for (int i = 0; i < 16; ++i) {
        const int e = e0 + i * 256 + t;
        if (e < N_EDGES) {
            const int d = dst[e];
            dcache[i] = d;
            atomicAdd(&lcnt[d >> 8], 1);
        } else dcache[i] = -1;
    }
    __syncthreads();
    for (int i = t; i < NBKT; i += 256) {
        gb[i] = rowp[i << 8] + atomicAdd(&bfill[i], lcnt[i]);
        lf[i] = 0;
    }
    __syncthreads();
#pragma unroll
    for (int i = 0; i < 16; ++i) {
        const int e = e0 + i * 256 + t;
        if (e < N_EDGES) {
            const int d = dcache[i];
            const int b = d >> 8;
            const int r = atomicAdd(&lf[b], 1);
            stage[gb[b] + r] = make_int2(src[e], d);
        }
    }
}

__global__ void __launch_bounds__(256) k_bscatter(const int2* __restrict__ stage,
                                                  const int* __restrict__ rowp,
                                                  int* __restrict__ col) {
    __shared__ int srow[257];
    __shared__ int lf[256];
    const int t = threadIdx.x;
    const int n0 = blockIdx.x << 8;
    for (int i = t; i < 257; i += 256) srow[i] = rowp[min(n0 + i, N_NODES)];
    lf[t] = 0;
    __syncthreads();
    const int base = srow[0], end = srow[256];
    for (int j = base + t; j < end; j += 256) {
        const int2 e = stage[j];
        const int local = e.y - n0;
        const int pos = srow[local] + atomicAdd(&lf[local], 1);
        col[pos] = e.x;
    }
}

// ---------------- el/er: el[n][h] = sum_k x[n,k]*Wa[k][h]; float4 [N][4] -----
template <int K, int F, typename XT>
__global__ void __launch_bounds__(256) k_el(const XT* __restrict__ x,
                                            const float* __restrict__ W,
                                            const float* __restrict__ al,
                                            const float* __restrict__ ar,
                                            float* __restrict__ el,
                                            float* __restrict__ er) {
    __shared__ float sWa[K * 3];
    __shared__ float sWr[K * 3];
    const int t = threadIdx.x;
    if (t < 3 * K) {
        const int h = t / K, k = t % K;
        float sa = 0.f, sr = 0.f;
        for (int f = 0; f < F; ++f) {
            const float w = W[k * 3 * F + h * F + f];
            sa += w * al[h * F + f];
            sr += w * ar[h * F + f];
        }
        sWa[k * 3 + h] = sa;
        sWr[k * 3 + h] = sr;
    }
    __syncthreads();
    const int n = blockIdx.x * 256 + t;
    if (n >= N_NODES) return;
    const XT* __restrict__ xr = x + (size_t)n * K;
    float a0 = 0.f, a1 = 0.f, a2 = 0.f, r0 = 0.f, r1 = 0.f, r2 = 0.f;
#pragma unroll 4
    for (int k = 0; k < K; ++k) {
        const float xv = to_f(xr[k]);
        a0 += xv * sWa[k * 3 + 0];
        a1 += xv * sWa[k * 3 + 1];
        a2 += xv * sWa[k * 3 + 2];
        r0 += xv * sWr[k * 3 + 0];
        r1 += xv * sWr[k * 3 + 1];
        r2 += xv * sWr[k * 3 + 2];
    }
    *reinterpret_cast<float4*>(el + (size_t)n * 4) = make_float4(a0, a1, a2, 0.f);
    *reinterpret_cast<float4*>(er + (size_t)n * 4) = make_float4(r0, r1, r2, 0.f);
}

// ---------------- L1 aggregation over INPUT features (K=9, fp32) -------------
// wave/node. lane = h*9+k (27 active in phase 2). agg [N][28], normalized.
__global__ void __launch_bounds__(256) k_aggw9(const float* __restrict__ x,
                                               const float* __restrict__ el,
                                               const float* __restrict__ er,
                                               const int* __restrict__ rowp,
                                               const int* __restrict__ col,
                                               float* __restrict__ agg) {
    const int wv = threadIdx.x >> 6;
    const int lane = threadIdx.x & 63;
    const int n = blockIdx.x * 4 + wv;          // grid exact
    const int jb = rowp[n], je = rowp[n + 1];

    __shared__ float wbuf[4][3][68];
    const float4 er4 = *reinterpret_cast<const float4*>(er + (size_t)n * 4);
    const int h = lane < 27 ? lane / 9 : 0;
    const int k = lane < 27 ? lane % 9 : 0;
    float acc = 0.f;
    float sw0 = 0.f, sw1 = 0.f, sw2 = 0.f;

    for (int c0 = jb; c0 < je; c0 += 64) {
        const int cnt = min(64, je - c0);
        float w0 = 0.f, w1 = 0.f, w2 = 0.f;
        if (lane < cnt) {
            const int s = col[c0 + lane];
            const float4 e4 = *reinterpret_cast<const float4*>(el + (size_t)s * 4);
            w0 = __expf(lrelu(e4.x + er4.x));
            w1 = __expf(lrelu(e4.y + er4.y));
            w2 = __expf(lrelu(e4.z + er4.z));
            wbuf[wv][0][lane] = w0;
            wbuf[wv][1][lane] = w1;
            wbuf[wv][2][lane] = w2;
        }
        sw0 += w0; sw1 += w1; sw2 += w2;
        if (lane < 27) {
            const float* __restrict__ wrow = &wbuf[wv][h][0];
            int e = 0;
            for (; e + 4 <= cnt; e += 4) {
                const int sA = __builtin_amdgcn_readfirstlane(col[c0 + e + 0]);
                const int sB = __builtin_amdgcn_readfirstlane(col[c0 + e + 1]);
                const int sC = __builtin_amdgcn_readfirstlane(col[c0 + e + 2]);
                const int sD = __builtin_amdgcn_readfirstlane(col[c0 + e + 3]);
                const float xA = x[(size_t)sA * 9 + k];
                const float xB = x[(size_t)sB * 9 + k];
                const float xC = x[(size_t)sC * 9 + k];
                const float xD = x[(size_t)sD * 9 + k];
                acc += wrow[e + 0] * xA + wrow[e + 1] * xB
                     + wrow[e + 2] * xC + wrow[e + 3] * xD;
            }
            for (; e < cnt; ++e) {
                const int s = __builtin_amdgcn_readfirstlane(col[c0 + e]);
                acc += wrow[e] * x[(size_t)s * 9 + k];
            }
        }
    }
#pragma unroll
    for (int off = 32; off > 0; off >>= 1) {
        sw0 += __shfl_xor(sw0, off);
        sw1 += __shfl_xor(sw1, off);
        sw2 += __shfl_xor(sw2, off);
    }
    if (lane < 27) {
        const float swh = (h == 0) ? sw0 : (h == 1 ? sw1 : sw2);
        agg[(size_t)n * 28 + lane] = (je > jb) ? acc / swh : 0.f;
    }
}

// ---------------- L2 aggregation over hidden (fp16 [N][64] table) ------------
// wave/node. lane = feature k. 3 head accumulators per lane. agg [N][192].
__global__ void __launch_bounds__(256) k_aggw64(const __half* __restrict__ x,
                                                const float* __restrict__ el,
                                                const float* __restrict__ er,
                                                const int* __restrict__ rowp,
                                                const int* __restrict__ col,
                                                float* __restrict__ agg) {
    const int wv = threadIdx.x >> 6;
    const int lane = threadIdx.x & 63;
    const int n = blockIdx.x * 4 + wv;          // grid exact
    const int jb = rowp[n], je = rowp[n + 1];

    __shared__ float wbuf[4][3][68];
    const float4 er4 = *reinterpret_cast<const float4*>(er + (size_t)n * 4);
    float a0 = 0.f, a1 = 0.f, a2 = 0.f;
    float sw0 = 0.f, sw1 = 0.f, sw2 = 0.f;

    for (int c0 = jb; c0 < je; c0 += 64) {
        const int cnt = min(64, je - c0);
        float w0 = 0.f, w1 = 0.f, w2 = 0.f;
        if (lane < cnt) {
            const int s = col[c0 + lane];
            const float4 e4 = *reinterpret_cast<const float4*>(el + (size_t)s * 4);
            w0 = __expf(lrelu(e4.x + er4.x));
            w1 = __expf(lrelu(e4.y + er4.y));
            w2 = __expf(lrelu(e4.z + er4.z));
            wbuf[wv][0][lane] = w0;
            wbuf[wv][1][lane] = w1;
            wbuf[wv][2][lane] = w2;
        }
        sw0 += w0; sw1 += w1; sw2 += w2;
        {
            int e = 0;
            for (; e + 4 <= cnt; e += 4) {
                const int sA = __builtin_amdgcn_readfirstlane(col[c0 + e + 0]);
                const int sB = __builtin_amdgcn_readfirstlane(col[c0 + e + 1]);
                const int sC = __builtin_amdgcn_readfirstlane(col[c0 + e + 2]);
                const int sD = __builtin_amdgcn_readfirstlane(col[c0 + e + 3]);
                const float xA = __half2float(x[(size_t)sA * 64 + lane]);
                const float xB = __half2float(x[(size_t)sB * 64 + lane]);
                const float xC = __half2float(x[(size_t)sC * 64 + lane]);
                const float xD = __half2float(x[(size_t)sD * 64 + lane]);
#pragma unroll
                for (int q = 0; q < 1; ++q) {}  // (keep structure flat)
                const float wA0 = wbuf[wv][0][e + 0], wA1 = wbuf[wv][1][e + 0], wA2 = wbuf[wv][2][e + 0];
                const float wB0 = wbuf[wv][0][e + 1], wB1 = wbuf[wv][1][e + 1], wB2 = wbuf[wv][2][e + 1];
                const float wC0 = wbuf[wv][0][e + 2], wC1 = wbuf[wv][1][e + 2], wC2 = wbuf[wv][2][e + 2];
                const float wD0 = wbuf[wv][0][e + 3], wD1 = wbuf[wv][1][e + 3], wD2 = wbuf[wv][2][e + 3];
                a0 += wA0 * xA + wB0 * xB + wC0 * xC + wD0 * xD;
                a1 += wA1 * xA + wB1 * xB + wC1 * xC + wD1 * xD;
                a2 += wA2 * xA + wB2 * xB + wC2 * xC + wD2 * xD;
            }
            for (; e < cnt; ++e) {
                const int s = __builtin_amdgcn_readfirstlane(col[c0 + e]);
                const float xv = __half2float(x[(size_t)s * 64 + lane]);
                a0 += wbuf[wv][0][e] * xv;
                a1 += wbuf[wv][1][e] * xv;
                a2 += wbuf[wv][2][e] * xv;
            }
        }
    }
#pragma unroll
    for (int off = 32; off > 0; off >>= 1) {
        sw0 += __shfl_xor(sw0, off);
        sw1 += __shfl_xor(sw1, off);
        sw2 += __shfl_xor(sw2, off);
    }
    float* __restrict__ ao = agg + (size_t)n * 192;
    if (je > jb) {
        ao[lane]       = a0 / sw0;
        ao[64 + lane]  = a1 / sw1;
        ao[128 + lane] = a2 / sw2;
    } else {
        ao[lane] = 0.f; ao[64 + lane] = 0.f; ao[128 + lane] = 0.f;
    }
}

// ---------------- post-agg GEMM: out[n,c] = sum_h agg_h[n,:] @ W[:,h*64+c] ---
// block = 192 thr = 3 waves; wave h computes its head's partial; LDS combine.
// Writes hidden as fp16 [N][64].
template <int KE, int AS, int NPB>
__global__ void __launch_bounds__(192) k_gemm(const float* __restrict__ agg,
                                              const float* __restrict__ W,
                                              const float* __restrict__ bias,
                                              __half* __restrict__ hout) {
    const int h = threadIdx.x >> 6;
    const int c = threadIdx.x & 63;
    float wreg[KE];
#pragma unroll
    for (int k = 0; k < KE; ++k) wreg[k] = W[k * 192 + h * 64 + c];

    const int nbase = blockIdx.x * NPB;         // grid exact
    const float* ar[NPB];
#pragma unroll
    for (int i = 0; i < NPB; ++i) {
        const int n = __builtin_amdgcn_readfirstlane(nbase + i);
        ar[i] = agg + (size_t)n * AS + h * KE;
    }
    float acc[NPB];
#pragma unroll
    for (int i = 0; i < NPB; ++i) acc[i] = 0.f;
#pragma unroll
    for (int k = 0; k < KE; ++k) {
        const float w = wreg[k];
#pragma unroll
        for (int i = 0; i < NPB; ++i) acc[i] += ar[i][k] * w;
    }

    __shared__ float part[3][NPB][64];
#pragma unroll
    for (int i = 0; i < NPB; ++i) part[h][i][c] = acc[i];
    __syncthreads();
    const float bsum = bias[c] + bias[64 + c] + bias[128 + c];
    for (int idx = threadIdx.x; idx < NPB * 64; idx += 192) {
        const int i = idx >> 6, cc = idx & 63;
        const float v = part[0][i][cc] + part[1][i][cc] + part[2][i][cc]
                      + bias[cc] + bias[64 + cc] + bias[128 + cc];
        hout[(size_t)(nbase + i) * 64 + cc] = __float2half(v);
    }
    (void)bsum;
}

// ---------------- layer 3: feat3 = h @ W3 (64->6), h is fp16 -----------------
__global__ void __launch_bounds__(256) k_feat3(const __half* __restrict__ x,
                                               const float* __restrict__ W3,
                                               float* __restrict__ feat3) {
    __shared__ float Wl[64 * 6];
    __shared__ float xl[32 * 64];
    const int t = threadIdx.x;
    const int n0 = blockIdx.x * 32;
    const int nvalid = min(32, N_NODES - n0);
    for (int idx = t; idx < 384; idx += 256) Wl[idx] = W3[idx];
    for (int idx = t; idx < nvalid * 64; idx += 256)
        xl[idx] = __half2float(x[(size_t)n0 * 64 + idx]);
    __syncthreads();

    const int i = t >> 3;
    const int slot = t & 7;
    if (i < nvalid && slot < 6) {
        float acc = 0.f;
#pragma unroll
        for (int k4 = 0; k4 < 16; ++k4) {
            const float4 xv = *reinterpret_cast<const float4*>(&xl[i * 64 + 4 * k4]);
            acc += Wl[(4 * k4 + 0) * 6 + slot] * xv.x;
            acc += Wl[(4 * k4 + 1) * 6 + slot] * xv.y;
            acc += Wl[(4 * k4 + 2) * 6 + slot] * xv.z;
            acc += Wl[(4 * k4 + 3) * 6 + slot] * xv.w;
        }
        feat3[(size_t)(n0 + i) * 8 + slot] = acc;
    }
}

// ---------------- layer-3 aggregation: 8 lanes/node, inline weights ----------
__global__ void __launch_bounds__(256) k_agg3(const float* __restrict__ feat3,
                                              const float* __restrict__ el3,
                                              const float* __restrict__ er3,
                                              const float* __restrict__ b3,
                                              const int* __restrict__ rowp,
                                              const int* __restrict__ col,
                                              float* __restrict__ out) {
    const int t = blockIdx.x * blockDim.x + threadIdx.x;
    const int n = t >> 3;
    const int r = t & 7;       // feature slot (0..5 valid; head = r/2)
    if (n >= N_NODES) return;
    int hh = r >> 1; if (hh > 2) hh = 2;
    const float ern = er3[(size_t)n * 4 + hh];
    const int jb = rowp[n], je = rowp[n + 1];
    float a = 0.f, sw = 0.f;
    for (int j = jb; j < je; ++j) {
        const int s = col[j];
        const float w = __expf(lrelu(el3[(size_t)s * 4 + hh] + ern));
        const float f = feat3[(size_t)s * 8 + r];
        a += w * f;
        sw += w;
    }
    float v = (je > jb && r < 6) ? (a / sw) : 0.f;
    v += __shfl_down(v, 2, 8);
    v += __shfl_down(v, 4, 8);
    if (r < 2) {
        const float bc = b3[r] + b3[r + 2] + b3[r + 4];
        out[(size_t)n * 2 + r] = v + bc;
    }
}

extern "C" void kernel_launch(void* const* d_in, const int* in_sizes, int n_in,
                              void* d_out, int out_size, void* d_ws, size_t ws_size,
                              hipStream_t stream) {
    const float* feats = (const float*)d_in[0];
    const int* src = (const int*)d_in[1];
    const int* dst = (const int*)d_in[2];
    const float* W1 = (const float*)d_in[3];
    const float* al1 = (const float*)d_in[4];
    const float* ar1 = (const float*)d_in[5];
    const float* b1 = (const float*)d_in[6];
    const float* W2 = (const float*)d_in[7];
    const float* al2 = (const float*)d_in[8];
    const float* ar2 = (const float*)d_in[9];
    const float* b2 = (const float*)d_in[10];
    const float* W3 = (const float*)d_in[11];
    const float* al3 = (const float*)d_in[12];
    const float* ar3 = (const float*)d_in[13];
    const float* b3 = (const float*)d_in[14];
    float* out = (float*)d_out;

    char* ws = (char*)d_ws;
    size_t off = 0;
    auto alloc = [&](size_t bytes) {
        void* p = ws + off;
        off += (bytes + 255) & ~(size_t)255;
        return p;
    };
    float* agg = (float*)alloc((size_t)N_NODES * 192 * 4);     // 38.4 MB (L1 uses [N][28])
    __half* hbufH = (__half*)alloc((size_t)N_NODES * 64 * 2);  // 6.4 MB fp16 hidden
    float* el = (float*)alloc((size_t)N_NODES * 4 * 4);
    float* er = (float*)alloc((size_t)N_NODES * 4 * 4);
    int* deg = (int*)alloc(((size_t)DEG_PAD + 256) * 4);       // deg + bfill, one memset
    int* bfill = deg + DEG_PAD;
    int* rowp = (int*)alloc((size_t)(N_NODES + 1) * 4);
    int* col = (int*)alloc((size_t)N_EDGES * 4);
    int2* stage = (int2*)alloc((size_t)N_EDGES * 8);
    int* bsum = (int*)alloc(64 * 4);
    int* boff = (int*)alloc(64 * 4);
    float* feat3 = (float*)alloc((size_t)N_NODES * 8 * 4);
    (void)ws_size;

    // ---- CSR build ----
    hipMemsetAsync(deg, 0, ((size_t)DEG_PAD + 256) * 4, stream);
    int eb = (N_EDGES + 255) / 256;
    k_count<<<eb, 256, 0, stream>>>(dst, deg);
    k_scanA<<<NB_SCAN, 256, 0, stream>>>(deg, bsum);
    k_scanB<<<1, 64, 0, stream>>>(bsum, boff, rowp);
    k_scanC<<<NB_SCAN, 256, 0, stream>>>(deg, boff, rowp);
    k_bin<<<NB_BIN, 256, 0, stream>>>(src, dst, rowp, bfill, stage);
    k_bscatter<<<NBKT, 256, 0, stream>>>(stage, rowp, col);

    const int ab = N_NODES / 4;             // wave/node kernels: 4 waves/block
    const int gb = N_NODES / 8;             // k_gemm: 8 nodes/block (6250)
    const int nb = (N_NODES + 255) / 256;
    const int nb3 = (N_NODES + 31) / 32;

    // ---- layer 1: aggregate INPUT features (1.8 MB table), then GEMM -------
    k_el<9, 64, float><<<nb, 256, 0, stream>>>(feats, W1, al1, ar1, el, er);
    k_aggw9<<<ab, 256, 0, stream>>>(feats, el, er, rowp, col, agg);
    k_gemm<9, 28, 8><<<gb, 192, 0, stream>>>(agg, W1, b1, hbufH);

    // ---- layer 2: aggregate fp16 hidden (6.4 MB table), then GEMM ----------
    k_el<64, 64, __half><<<nb, 256, 0, stream>>>(hbufH, W2, al2, ar2, el, er);
    k_aggw64<<<ab, 256, 0, stream>>>(hbufH, el, er, rowp, col, agg);
    k_gemm<64, 192, 8><<<gb, 192, 0, stream>>>(agg, W2, b2, hbufH);

    // ---- layer 3 ----
    k_el<64, 2, __half><<<nb, 256, 0, stream>>>(hbufH, W3, al3, ar3, el, er);
    k_feat3<<<nb3, 256, 0, stream>>>(hbufH, W3, feat3);
    k_agg3<<<nb3, 256, 0, stream>>>(feat3, el, er, b3, rowp, col, out);
}

// Round 13
// 308.647 us; speedup vs baseline: 1.1790x; 1.1790x over previous
//
#include <hip/hip_runtime.h>
#include <hip/hip_fp16.h>

#define N_NODES 50000
#define N_EDGES 800000
#define NB_SCAN 49          // ceil(50000 / 1024)
#define DEG_PAD (NB_SCAN * 1024)   // 50176, zero-padded so int4 loads are unguarded
#define NBKT 196            // ceil(50000 / 256) coarse buckets (dst >> 8)
#define EPB_BIN 4096        // edges per k_bin block
#define NB_BIN ((N_EDGES + EPB_BIN - 1) / EPB_BIN)   // 196

static __device__ __forceinline__ float lrelu(float x) { return fmaxf(x, 0.2f * x); }
static __device__ __forceinline__ float to_f(float x) { return x; }
static __device__ __forceinline__ float to_f(__half x) { return __half2float(x); }

// ---------------- CSR build ----------------
__global__ void k_count(const int* __restrict__ dst, int* __restrict__ deg) {
    int e = blockIdx.x * blockDim.x + threadIdx.x;
    if (e < N_EDGES) atomicAdd(&deg[dst[e]], 1);
}

__global__ void __launch_bounds__(256) k_scanA(const int* __restrict__ deg,
                                               int* __restrict__ bsum) {
    const int t = threadIdx.x;
    const int b = blockIdx.x;
    const int base = (b * 256 + t) * 4;
    const int4 v = *reinterpret_cast<const int4*>(deg + base);  // padded: safe
    int s = v.x + v.y + v.z + v.w;
#pragma unroll
    for (int off = 32; off > 0; off >>= 1) s += __shfl_down(s, off);
    __shared__ int ws[4];
    if ((t & 63) == 0) ws[t >> 6] = s;
    __syncthreads();
    if (t == 0) bsum[b] = ws[0] + ws[1] + ws[2] + ws[3];
}

__global__ void __launch_bounds__(64) k_scanB(const int* __restrict__ bsum,
                                              int* __restrict__ boff,
                                              int* __restrict__ rowp) {
    const int t = threadIdx.x;
    const int v = (t < NB_SCAN) ? bsum[t] : 0;
    int inc = v;
#pragma unroll
    for (int off = 1; off < 64; off <<= 1) {
        const int u = __shfl_up(inc, off);
        if (t >= off) inc += u;
    }
    if (t < NB_SCAN) boff[t] = inc - v;
    if (t == 0) rowp[N_NODES] = N_EDGES;
}

__global__ void __launch_bounds__(256) k_scanC(const int* __restrict__ deg,
                                               const int* __restrict__ boff,
                                               int* __restrict__ rowp) {
    const int t = threadIdx.x;
    const int b = blockIdx.x;
    const int lane = t & 63;
    const int wv = t >> 6;
    const int base = (b * 256 + t) * 4;
    const int4 v = *reinterpret_cast<const int4*>(deg + base);
    const int s = v.x + v.y + v.z + v.w;
    int inc = s;
#pragma unroll
    for (int off = 1; off < 64; off <<= 1) {
        const int u = __shfl_up(inc, off);
        if (lane >= off) inc += u;
    }
    __shared__ int wsum[4];
    if (lane == 63) wsum[wv] = inc;
    __syncthreads();
    int add = boff[b];
    for (int w = 0; w < wv; ++w) add += wsum[w];
    const int exc = add + inc - s;
    if (base < N_NODES) rowp[base] = exc;
    if (base + 1 < N_NODES) rowp[base + 1] = exc + v.x;
    if (base + 2 < N_NODES) rowp[base + 2] = exc + v.x + v.y;
    if (base + 3 < N_NODES) rowp[base + 3] = exc + v.x + v.y + v.z;
}

// ---------------- binned scatter (two phase, XCD-local line ownership) -------
__global__ void __launch_bounds__(256) k_bin(const int* __restrict__ src,
                                             const int* __restrict__ dst,
                                             const int* __restrict__ rowp,
                                             int* __restrict__ bfill,
                                             int2* __restrict__ stage) {
    __shared__ int lcnt[NBKT];
    __shared__ int gb[NBKT];
    __shared__ int lf[NBKT];
    const int t = threadIdx.x;
    const int e0 = blockIdx.x * EPB_BIN;
    for (int i = t; i < NBKT; i += 256) lcnt[i] = 0;
    __syncthreads();
    int dcache[16];
#pragma unroll
    for (int i = 0; i < 16; ++i) {
        const int e = e0 + i * 256 + t;
        if (e < N_EDGES) {
            const int d = dst[e];
            dcache[i] = d;
            atomicAdd(&lcnt[d >> 8], 1);
        } else dcache[i] = -1;
    }
    __syncthreads();
    for (int i = t; i < NBKT; i += 256) {
        gb[i] = rowp[i << 8] + atomicAdd(&bfill[i], lcnt[i]);
        lf[i] = 0;
    }
    __syncthreads();
#pragma unroll
    for (int i = 0; i < 16; ++i) {
        const int e = e0 + i * 256 + t;
        if (e < N_EDGES) {
            const int d = dcache[i];
            const int b = d >> 8;
            const int r = atomicAdd(&lf[b], 1);
            stage[gb[b] + r] = make_int2(src[e], d);
        }
    }
}

__global__ void __launch_bounds__(256) k_bscatter(const int2* __restrict__ stage,
                                                  const int* __restrict__ rowp,
                                                  int* __restrict__ col) {
    __shared__ int srow[257];
    __shared__ int lf[256];
    const int t = threadIdx.x;
    const int n0 = blockIdx.x << 8;
    for (int i = t; i < 257; i += 256) srow[i] = rowp[min(n0 + i, N_NODES)];
    lf[t] = 0;
    __syncthreads();
    const int base = srow[0], end = srow[256];
    for (int j = base + t; j < end; j += 256) {
        const int2 e = stage[j];
        const int local = e.y - n0;
        const int pos = srow[local] + atomicAdd(&lf[local], 1);
        col[pos] = e.x;
    }
}

// ---------------- el/er: el[n][h] = sum_k x[n,k]*Wa[k][h]; float4 [N][4] -----
template <int K, int F, typename XT>
__global__ void __launch_bounds__(256) k_el(const XT* __restrict__ x,
                                            const float* __restrict__ W,
                                            const float* __restrict__ al,
                                            const float* __restrict__ ar,
                                            float* __restrict__ el,
                                            float* __restrict__ er) {
    __shared__ float sWa[K * 3];
    __shared__ float sWr[K * 3];
    const int t = threadIdx.x;
    if (t < 3 * K) {
        const int h = t / K, k = t % K;
        float sa = 0.f, sr = 0.f;
        for (int f = 0; f < F; ++f) {
            const float w = W[k * 3 * F + h * F + f];
            sa += w * al[h * F + f];
            sr += w * ar[h * F + f];
        }
        sWa[k * 3 + h] = sa;
        sWr[k * 3 + h] = sr;
    }
    __syncthreads();
    const int n = blockIdx.x * 256 + t;
    if (n >= N_NODES) return;
    const XT* __restrict__ xr = x + (size_t)n * K;
    float a0 = 0.f, a1 = 0.f, a2 = 0.f, r0 = 0.f, r1 = 0.f, r2 = 0.f;
#pragma unroll 4
    for (int k = 0; k < K; ++k) {
        const float xv = to_f(xr[k]);
        a0 += xv * sWa[k * 3 + 0];
        a1 += xv * sWa[k * 3 + 1];
        a2 += xv * sWa[k * 3 + 2];
        r0 += xv * sWr[k * 3 + 0];
        r1 += xv * sWr[k * 3 + 1];
        r2 += xv * sWr[k * 3 + 2];
    }
    *reinterpret_cast<float4*>(el + (size_t)n * 4) = make_float4(a0, a1, a2, 0.f);
    *reinterpret_cast<float4*>(er + (size_t)n * 4) = make_float4(r0, r1, r2, 0.f);
}

// ---------------- L1 aggregation over INPUT features (K=9, fp32) -------------
__global__ void __launch_bounds__(256) k_aggw9(const float* __restrict__ x,
                                               const float* __restrict__ el,
                                               const float* __restrict__ er,
                                               const int* __restrict__ rowp,
                                               const int* __restrict__ col,
                                               float* __restrict__ agg) {
    const int wv = threadIdx.x >> 6;
    const int lane = threadIdx.x & 63;
    const int n = blockIdx.x * 4 + wv;          // grid exact
    const int jb = rowp[n], je = rowp[n + 1];

    __shared__ float wbuf[4][3][68];
    const float4 er4 = *reinterpret_cast<const float4*>(er + (size_t)n * 4);
    const int h = lane < 27 ? lane / 9 : 0;
    const int k = lane < 27 ? lane % 9 : 0;
    float acc = 0.f;
    float sw0 = 0.f, sw1 = 0.f, sw2 = 0.f;

    for (int c0 = jb; c0 < je; c0 += 64) {
        const int cnt = min(64, je - c0);
        float w0 = 0.f, w1 = 0.f, w2 = 0.f;
        if (lane < cnt) {
            const int s = col[c0 + lane];
            const float4 e4 = *reinterpret_cast<const float4*>(el + (size_t)s * 4);
            w0 = __expf(lrelu(e4.x + er4.x));
            w1 = __expf(lrelu(e4.y + er4.y));
            w2 = __expf(lrelu(e4.z + er4.z));
            wbuf[wv][0][lane] = w0;
            wbuf[wv][1][lane] = w1;
            wbuf[wv][2][lane] = w2;
        }
        sw0 += w0; sw1 += w1; sw2 += w2;
        if (lane < 27) {
            const float* __restrict__ wrow = &wbuf[wv][h][0];
            int e = 0;
            for (; e + 4 <= cnt; e += 4) {
                const int sA = __builtin_amdgcn_readfirstlane(col[c0 + e + 0]);
                const int sB = __builtin_amdgcn_readfirstlane(col[c0 + e + 1]);
                const int sC = __builtin_amdgcn_readfirstlane(col[c0 + e + 2]);
                const int sD = __builtin_amdgcn_readfirstlane(col[c0 + e + 3]);
                const float xA = x[(size_t)sA * 9 + k];
                const float xB = x[(size_t)sB * 9 + k];
                const float xC = x[(size_t)sC * 9 + k];
                const float xD = x[(size_t)sD * 9 + k];
                acc += wrow[e + 0] * xA + wrow[e + 1] * xB
                     + wrow[e + 2] * xC + wrow[e + 3] * xD;
            }
            for (; e < cnt; ++e) {
                const int s = __builtin_amdgcn_readfirstlane(col[c0 + e]);
                acc += wrow[e] * x[(size_t)s * 9 + k];
            }
        }
    }
#pragma unroll
    for (int off = 32; off > 0; off >>= 1) {
        sw0 += __shfl_xor(sw0, off);
        sw1 += __shfl_xor(sw1, off);
        sw2 += __shfl_xor(sw2, off);
    }
    if (lane < 27) {
        const float swh = (h == 0) ? sw0 : (h == 1 ? sw1 : sw2);
        agg[(size_t)n * 28 + lane] = (je > jb) ? acc / swh : 0.f;
    }
    if (lane == 27) agg[(size_t)n * 28 + 27] = 0.f;
}

// ---------------- L2 aggregation over hidden (fp16 [N][64] table) ------------
__global__ void __launch_bounds__(256) k_aggw64(const __half* __restrict__ x,
                                                const float* __restrict__ el,
                                                const float* __restrict__ er,
                                                const int* __restrict__ rowp,
                                                const int* __restrict__ col,
                                                float* __restrict__ agg) {
    const int wv = threadIdx.x >> 6;
    const int lane = threadIdx.x & 63;
    const int n = blockIdx.x * 4 + wv;          // grid exact
    const int jb = rowp[n], je = rowp[n + 1];

    __shared__ float wbuf[4][3][68];
    const float4 er4 = *reinterpret_cast<const float4*>(er + (size_t)n * 4);
    float a0 = 0.f, a1 = 0.f, a2 = 0.f;
    float sw0 = 0.f, sw1 = 0.f, sw2 = 0.f;

    for (int c0 = jb; c0 < je; c0 += 64) {
        const int cnt = min(64, je - c0);
        float w0 = 0.f, w1 = 0.f, w2 = 0.f;
        if (lane < cnt) {
            const int s = col[c0 + lane];
            const float4 e4 = *reinterpret_cast<const float4*>(el + (size_t)s * 4);
            w0 = __expf(lrelu(e4.x + er4.x));
            w1 = __expf(lrelu(e4.y + er4.y));
            w2 = __expf(lrelu(e4.z + er4.z));
            wbuf[wv][0][lane] = w0;
            wbuf[wv][1][lane] = w1;
            wbuf[wv][2][lane] = w2;
        }
        sw0 += w0; sw1 += w1; sw2 += w2;
        {
            int e = 0;
            for (; e + 4 <= cnt; e += 4) {
                const int sA = __builtin_amdgcn_readfirstlane(col[c0 + e + 0]);
                const int sB = __builtin_amdgcn_readfirstlane(col[c0 + e + 1]);
                const int sC = __builtin_amdgcn_readfirstlane(col[c0 + e + 2]);
                const int sD = __builtin_amdgcn_readfirstlane(col[c0 + e + 3]);
                const float xA = __half2float(x[(size_t)sA * 64 + lane]);
                const float xB = __half2float(x[(size_t)sB * 64 + lane]);
                const float xC = __half2float(x[(size_t)sC * 64 + lane]);
                const float xD = __half2float(x[(size_t)sD * 64 + lane]);
                const float wA0 = wbuf[wv][0][e + 0], wA1 = wbuf[wv][1][e + 0], wA2 = wbuf[wv][2][e + 0];
                const float wB0 = wbuf[wv][0][e + 1], wB1 = wbuf[wv][1][e + 1], wB2 = wbuf[wv][2][e + 1];
                const float wC0 = wbuf[wv][0][e + 2], wC1 = wbuf[wv][1][e + 2], wC2 = wbuf[wv][2][e + 2];
                const float wD0 = wbuf[wv][0][e + 3], wD1 = wbuf[wv][1][e + 3], wD2 = wbuf[wv][2][e + 3];
                a0 += wA0 * xA + wB0 * xB + wC0 * xC + wD0 * xD;
                a1 += wA1 * xA + wB1 * xB + wC1 * xC + wD1 * xD;
                a2 += wA2 * xA + wB2 * xB + wC2 * xC + wD2 * xD;
            }
            for (; e < cnt; ++e) {
                const int s = __builtin_amdgcn_readfirstlane(col[c0 + e]);
                const float xv = __half2float(x[(size_t)s * 64 + lane]);
                a0 += wbuf[wv][0][e] * xv;
                a1 += wbuf[wv][1][e] * xv;
                a2 += wbuf[wv][2][e] * xv;
            }
        }
    }
#pragma unroll
    for (int off = 32; off > 0; off >>= 1) {
        sw0 += __shfl_xor(sw0, off);
        sw1 += __shfl_xor(sw1, off);
        sw2 += __shfl_xor(sw2, off);
    }
    float* __restrict__ ao = agg + (size_t)n * 192;
    if (je > jb) {
        ao[lane]       = a0 / sw0;
        ao[64 + lane]  = a1 / sw1;
        ao[128 + lane] = a2 / sw2;
    } else {
        ao[lane] = 0.f; ao[64 + lane] = 0.f; ao[128 + lane] = 0.f;
    }
}

// ---------------- post-agg GEMM, LDS-tiled: out[n,c] = sum_h agg_h[n]@W_h ----
// block = 192 thr (wave h = head). Tile NPB=16 nodes. Stage agg tile via
// coalesced float4 loads; compute from broadcast LDS reads; LDS head-combine.
// KE=K per head, AS=agg row stride, HOFF=head offset in agg row.
template <int KE, int AS, int HOFF>
__global__ void __launch_bounds__(192) k_gemm2(const float* __restrict__ agg,
                                               const float* __restrict__ W,
                                               const float* __restrict__ bias,
                                               __half* __restrict__ hout) {
    const int NPB = 16;
    const int h = threadIdx.x >> 6;
    const int c = threadIdx.x & 63;
    float wreg[KE];
#pragma unroll
    for (int k = 0; k < KE; ++k) wreg[k] = W[k * 192 + h * 64 + c];

    __shared__ float At[NPB * AS];
    __shared__ float part[3][NPB][64];
    const int nbase = blockIdx.x * NPB;         // 3125 * 16 = 50000 exact

    const float4* __restrict__ src4 =
        reinterpret_cast<const float4*>(agg + (size_t)nbase * AS);
    float4* At4 = reinterpret_cast<float4*>(At);
    for (int idx = threadIdx.x; idx < NPB * AS / 4; idx += 192) At4[idx] = src4[idx];
    __syncthreads();

#pragma unroll
    for (int i = 0; i < NPB; ++i) {
        const float* __restrict__ ar = At + i * AS + h * HOFF;
        float acc = 0.f;
        if (KE % 4 == 0) {
#pragma unroll
            for (int k4 = 0; k4 < KE / 4; ++k4) {
                const float4 a = *reinterpret_cast<const float4*>(ar + 4 * k4);
                acc += a.x * wreg[4 * k4 + 0] + a.y * wreg[4 * k4 + 1]
                     + a.z * wreg[4 * k4 + 2] + a.w * wreg[4 * k4 + 3];
            }
        } else {
#pragma unroll
            for (int k = 0; k < KE; ++k) acc += ar[k] * wreg[k];
        }
        part[h][i][c] = acc;
    }
    __syncthreads();
    for (int idx = threadIdx.x; idx < NPB * 64; idx += 192) {
        const int i = idx >> 6, cc = idx & 63;
        const float v = part[0][i][cc] + part[1][i][cc] + part[2][i][cc]
                      + bias[cc] + bias[64 + cc] + bias[128 + cc];
        hout[(size_t)(nbase + i) * 64 + cc] = __float2half(v);
    }
}

// ---------------- layer 3: feat3 = h @ W3 (64->6), h is fp16 -----------------
__global__ void __launch_bounds__(256) k_feat3(const __half* __restrict__ x,
                                               const float* __restrict__ W3,
                                               float* __restrict__ feat3) {
    __shared__ float Wl[64 * 6];
    __shared__ float xl[32 * 64];
    const int t = threadIdx.x;
    const int n0 = blockIdx.x * 32;
    const int nvalid = min(32, N_NODES - n0);
    for (int idx = t; idx < 384; idx += 256) Wl[idx] = W3[idx];
    for (int idx = t; idx < nvalid * 64; idx += 256)
        xl[idx] = __half2float(x[(size_t)n0 * 64 + idx]);
    __syncthreads();

    const int i = t >> 3;
    const int slot = t & 7;
    if (i < nvalid && slot < 6) {
        float acc = 0.f;
#pragma unroll
        for (int k4 = 0; k4 < 16; ++k4) {
            const float4 xv = *reinterpret_cast<const float4*>(&xl[i * 64 + 4 * k4]);
            acc += Wl[(4 * k4 + 0) * 6 + slot] * xv.x;
            acc += Wl[(4 * k4 + 1) * 6 + slot] * xv.y;
            acc += Wl[(4 * k4 + 2) * 6 + slot] * xv.z;
            acc += Wl[(4 * k4 + 3) * 6 + slot] * xv.w;
        }
        feat3[(size_t)(n0 + i) * 8 + slot] = acc;
    }
}

// ---------------- layer-3 aggregation: 8 lanes/node, inline weights ----------
__global__ void __launch_bounds__(256) k_agg3(const float* __restrict__ feat3,
                                              const float* __restrict__ el3,
                                              const float* __restrict__ er3,
                                              const float* __restrict__ b3,
                                              const int* __restrict__ rowp,
                                              const int* __restrict__ col,
                                              float* __restrict__ out) {
    const int t = blockIdx.x * blockDim.x + threadIdx.x;
    const int n = t >> 3;
    const int r = t & 7;       // feature slot (0..5 valid; head = r/2)
    if (n >= N_NODES) return;
    int hh = r >> 1; if (hh > 2) hh = 2;
    const float ern = er3[(size_t)n * 4 + hh];
    const int jb = rowp[n], je = rowp[n + 1];
    float a = 0.f, sw = 0.f;
    for (int j = jb; j < je; ++j) {
        const int s = col[j];
        const float w = __expf(lrelu(el3[(size_t)s * 4 + hh] + ern));
        const float f = feat3[(size_t)s * 8 + r];
        a += w * f;
        sw += w;
    }
    float v = (je > jb && r < 6) ? (a / sw) : 0.f;
    v += __shfl_down(v, 2, 8);
    v += __shfl_down(v, 4, 8);
    if (r < 2) {
        const float bc = b3[r] + b3[r + 2] + b3[r + 4];
        out[(size_t)n * 2 + r] = v + bc;
    }
}

extern "C" void kernel_launch(void* const* d_in, const int* in_sizes, int n_in,
                              void* d_out, int out_size, void* d_ws, size_t ws_size,
                              hipStream_t stream) {
    const float* feats = (const float*)d_in[0];
    const int* src = (const int*)d_in[1];
    const int* dst = (const int*)d_in[2];
    const float* W1 = (const float*)d_in[3];
    const float* al1 = (const float*)d_in[4];
    const float* ar1 = (const float*)d_in[5];
    const float* b1 = (const float*)d_in[6];
    const float* W2 = (const float*)d_in[7];
    const float* al2 = (const float*)d_in[8];
    const float* ar2 = (const float*)d_in[9];
    const float* b2 = (const float*)d_in[10];
    const float* W3 = (const float*)d_in[11];
    const float* al3 = (const float*)d_in[12];
    const float* ar3 = (const float*)d_in[13];
    const float* b3 = (const float*)d_in[14];
    float* out = (float*)d_out;

    char* ws = (char*)d_ws;
    size_t off = 0;
    auto alloc = [&](size_t bytes) {
        void* p = ws + off;
        off += (bytes + 255) & ~(size_t)255;
        return p;
    };
    float* agg = (float*)alloc((size_t)N_NODES * 192 * 4);     // L1 uses [N][28]
    __half* hbufH = (__half*)alloc((size_t)N_NODES * 64 * 2);  // 6.4 MB fp16 hidden
    float* el = (float*)alloc((size_t)N_NODES * 4 * 4);
    float* er = (float*)alloc((size_t)N_NODES * 4 * 4);
    int* deg = (int*)alloc(((size_t)DEG_PAD + 256) * 4);       // deg + bfill, one memset
    int* bfill = deg + DEG_PAD;
    int* rowp = (int*)alloc((size_t)(N_NODES + 1) * 4);
    int* col = (int*)alloc((size_t)N_EDGES * 4);
    int2* stage = (int2*)alloc((size_t)N_EDGES * 8);
    int* bsum = (int*)alloc(64 * 4);
    int* boff = (int*)alloc(64 * 4);
    float* feat3 = (float*)alloc((size_t)N_NODES * 8 * 4);
    (void)ws_size;

    // ---- CSR build ----
    hipMemsetAsync(deg, 0, ((size_t)DEG_PAD + 256) * 4, stream);
    int eb = (N_EDGES + 255) / 256;
    k_count<<<eb, 256, 0, stream>>>(dst, deg);
    k_scanA<<<NB_SCAN, 256, 0, stream>>>(deg, bsum);
    k_scanB<<<1, 64, 0, stream>>>(bsum, boff, rowp);
    k_scanC<<<NB_SCAN, 256, 0, stream>>>(deg, boff, rowp);
    k_bin<<<NB_BIN, 256, 0, stream>>>(src, dst, rowp, bfill, stage);
    k_bscatter<<<NBKT, 256, 0, stream>>>(stage, rowp, col);

    const int ab = N_NODES / 4;             // wave/node kernels: 4 waves/block
    const int gb2 = N_NODES / 16;           // k_gemm2: 16 nodes/block (3125)
    const int nb = (N_NODES + 255) / 256;
    const int nb3 = (N_NODES + 31) / 32;

    // ---- layer 1: aggregate INPUT features (1.8 MB table), then GEMM -------
    k_el<9, 64, float><<<nb, 256, 0, stream>>>(feats, W1, al1, ar1, el, er);
    k_aggw9<<<ab, 256, 0, stream>>>(feats, el, er, rowp, col, agg);
    k_gemm2<9, 28, 9><<<gb2, 192, 0, stream>>>(agg, W1, b1, hbufH);

    // ---- layer 2: aggregate fp16 hidden (6.4 MB table), then GEMM ----------
    k_el<64, 64, __half><<<nb, 256, 0, stream>>>(hbufH, W2, al2, ar2, el, er);
    k_aggw64<<<ab, 256, 0, stream>>>(hbufH, el, er, rowp, col, agg);
    k_gemm2<64, 192, 64><<<gb2, 192, 0, stream>>>(agg, W2, b2, hbufH);

    // ---- layer 3 ----
    k_el<64, 2, __half><<<nb, 256, 0, stream>>>(hbufH, W3, al3, ar3, el, er);
    k_feat3<<<nb3, 256, 0, stream>>>(hbufH, W3, feat3);
    k_agg3<<<nb3, 256, 0, stream>>>(feat3, el, er, b3, rowp, col, out);
}